// Round 15
// baseline (1727.880 us; speedup 1.0000x reference)
//
#include <hip/hip_runtime.h>
#include <cstddef>

#define BN 32
#define TN 256
#define PW 68
#define PLANE 4488   // 66 rows x 68 px; interior rows 1..64, cols 2..65

typedef __attribute__((ext_vector_type(8))) short bf16x8;
typedef __attribute__((ext_vector_type(4))) float f32x4;

struct __attribute__((aligned(16))) U4 { unsigned x, y, z, w; };

__device__ __forceinline__ float silu_f(float v) { return v / (1.f + __expf(-v)); }

__device__ __forceinline__ unsigned short f2bf(float f) {
  unsigned u = __float_as_uint(f);
  unsigned r = (u + 0x7fffu + ((u >> 16) & 1u)) >> 16;
  return (unsigned short)r;
}
__device__ __forceinline__ float bf2f(unsigned short h) {
  return __uint_as_float((unsigned)h << 16);
}
__device__ __forceinline__ unsigned pack2(float a, float b) {
  return (unsigned)f2bf(a) | ((unsigned)f2bf(b) << 16);
}

// async 16B global->LDS; lds dest = wave-uniform base + lane*16
__device__ __forceinline__ void gld16(const unsigned short* g, unsigned short* l) {
  __builtin_amdgcn_global_load_lds((const __attribute__((address_space(1))) unsigned int*)g,
                                   (__attribute__((address_space(3))) unsigned int*)l, 16, 0, 0);
}

__global__ __launch_bounds__(256) void copy_kernel(const float* __restrict__ src, float* __restrict__ dst, int n) {
  int i = blockIdx.x * 256 + threadIdx.x;
  if (i < n) dst[i] = src[i];
}

__global__ __launch_bounds__(256) void zstats_kernel(float* __restrict__ s) {
  int i = blockIdx.x * 256 + threadIdx.x;
  if (i < 18 * 512) s[i] = 0.f;
}

// ---- zero the halo ring of S4/A4/B4 (384 contiguous planes); halo = rows 0,65 + cols 0,1,66,67 ----
__global__ __launch_bounds__(256) void zerohalo_kernel(unsigned short* __restrict__ base) {
  int idx = blockIdx.x * 256 + threadIdx.x;
  if (idx >= 384 * 1568) return;
  int p = idx / 1568, rem = idx % 1568;
  int hp = rem >> 2, icq = rem & 3;
  int row, x;
  if (hp < 68) { row = 0; x = hp; }
  else if (hp < 136) { row = 65; x = hp - 68; }
  else {
    int i = hp - 136;
    row = 1 + (i >> 2);
    const int cols[4] = {0, 1, 66, 67};
    x = cols[i & 3];
  }
  U4 z = {0u, 0u, 0u, 0u};
  *(U4*)&base[((size_t)p * PLANE + row * PW + x) * 32 + icq * 8] = z;
}

// ---- resize 128->64 (exact 2x2 avg) -> padded [b][2cc][66][68][32] bf16 ----
__global__ __launch_bounds__(256) void resize_t_kernel(const float* __restrict__ M, unsigned short* __restrict__ Ms4) {
  __shared__ unsigned short lt[4 * 64 * 72];
  int b = blockIdx.y, yt = blockIdx.x;
  int tid = threadIdx.x;
  for (int i = tid; i < 4 * 64 * 64; i += 256) {
    int c = i >> 8, y = (i >> 6) & 3, x = i & 63;
    const float* p = M + (((size_t)(b * 64 + c) * 128) + (yt * 4 + y) * 2) * 128 + 2 * x;
    float2 a = *(const float2*)p;
    float2 bq = *(const float2*)(p + 128);
    lt[(y * 64 + x) * 72 + c] = f2bf(0.25f * (a.x + a.y + bq.x + bq.y));
  }
  __syncthreads();
  for (int i = tid; i < 2048; i += 256) {
    int icq = i & 3, pxl = (i >> 2) & 255, cc = i >> 10;
    U4 q = *(const U4*)&lt[pxl * 72 + cc * 32 + icq * 8];
    int y = yt * 4 + (pxl >> 6), x = pxl & 63;
    *(U4*)&Ms4[(((size_t)(b * 2 + cc) * PLANE) + (size_t)(y + 1) * PW + x + 2) * 32 + icq * 8] = q;
  }
}

// ---- conv weight prep: W[oc][ic][3][3] fp32 -> [tap*4+cc][128 oc][32 ic] bf16 ----
__global__ __launch_bounds__(256) void wprep_kernel(const float* __restrict__ Wsrc, unsigned short* __restrict__ Wdst) {
  int idx = blockIdx.x * 256 + threadIdx.x;
  if (idx >= 147456) return;
  int icp = idx & 31;
  int oc = (idx >> 5) & 127;
  int tc = idx >> 12;
  int t = tc >> 2, cch = tc & 3;
  Wdst[idx] = f2bf(Wsrc[(size_t)oc * 1152 + (size_t)(cch * 32 + icp) * 9 + t]);
}

__global__ __launch_bounds__(256) void wprep_in_kernel(const float* __restrict__ ipw, unsigned short* __restrict__ wi) {
  int idx = blockIdx.x * 256 + threadIdx.x;
  if (idx >= 12288) return;
  int icp = idx & 31, oc = (idx >> 5) & 127, cc = idx >> 12;
  float f = 0.f;
  if (cc < 2) f = ipw[oc * 195 + cc * 32 + icp];
  else if (icp < 3) f = ipw[oc * 195 + 64 + icp];
  wi[idx] = f2bf(f);
}

__global__ __launch_bounds__(256) void wprep_out_kernel(const float* __restrict__ ow, unsigned short* __restrict__ wo) {
  int idx = blockIdx.x * 256 + threadIdx.x;
  if (idx >= 16384) return;
  int icp = idx & 31, oc = (idx >> 5) & 127, cc = idx >> 12;
  wo[idx] = f2bf(ow[oc * 128 + cc * 32 + icp]);
}

__global__ __launch_bounds__(256) void tctr_kernel(const float* __restrict__ w, const float* __restrict__ bias,
                                                   const float* __restrict__ te, float* __restrict__ tctr) {
  int i = blockIdx.x * 256 + threadIdx.x;
  if (i >= BN * 128) return;
  int b = i >> 7, o = i & 127;
  float acc = bias[o];
  const float* wp = w + (size_t)o * 195 + 67;
  const float* t = te + b * 128;
  #pragma unroll 8
  for (int k = 0; k < 128; ++k) acc += wp[k] * t[k];
  tctr[i] = acc;
}

__global__ __launch_bounds__(256) void tpart_kernel(const float* __restrict__ w1, const float* __restrict__ b1,
                                                    const float* __restrict__ te, float* __restrict__ tp) {
  int i = blockIdx.x * 256 + threadIdx.x;
  if (i >= BN * 128) return;
  int b = i >> 7, j = i & 127;
  float acc = b1[j];
  #pragma unroll 8
  for (int k = 0; k < 128; ++k) acc += te[b * 128 + k] * w1[(size_t)(128 + k) * 128 + j];
  tp[i] = acc;
}

// ---- rasterize -> padded Pp [b][66][68][32] bf16 (ch0=heat,1=vx,2=vy, rest 0) ----
__global__ __launch_bounds__(256) void raster4_kernel(const float* __restrict__ x, unsigned short* __restrict__ Pp) {
  int b = blockIdx.y, blk = blockIdx.x;
  int tid = threadIdx.x;
  int pix = blk * 256 + tid;
  __shared__ float spx[TN], spy[TN];
  __shared__ unsigned short lp[256 * 32];
  spx[tid] = (x[(b * TN + tid) * 2] + 1.f) * 0.5f * 63.f;
  spy[tid] = (x[(b * TN + tid) * 2 + 1] + 1.f) * 0.5f * 63.f;
  __syncthreads();
  float fx = (float)(pix & 63), fy = (float)(pix >> 6);
  const float coef = -0.5f / (1.44f + 1e-8f);
  float heat = 0.f, sx = 0.f, sy = 0.f, sw = 0.f;
  float prevx = 0.f, prevy = 0.f;
  for (int t = 0; t < TN; ++t) {
    float px = spx[t], py = spy[t];
    float ddx = px - fx, ddy = py - fy;
    float w = __expf(coef * (ddx * ddx + ddy * ddy));
    heat = fmaxf(heat, w);
    float vx = (t == 0) ? 0.f : px - prevx;
    float vy = (t == 0) ? 0.f : py - prevy;
    prevx = px; prevy = py;
    sx += w * vx; sy += w * vy; sw += w;
  }
  float inv = 1.f / fmaxf(sw, 1e-6f);
  U4 q0; q0.x = pack2(heat, sx * inv); q0.y = pack2(sy * inv, 0.f); q0.z = 0u; q0.w = 0u;
  U4 z = {0u, 0u, 0u, 0u};
  *(U4*)&lp[tid * 32 + 0] = q0;
  *(U4*)&lp[tid * 32 + 8] = z;
  *(U4*)&lp[tid * 32 + 16] = z;
  *(U4*)&lp[tid * 32 + 24] = z;
  __syncthreads();
  for (int it = 0; it < 4; ++it) {
    int sid = it * 256 + tid;
    int pxl = sid >> 2, icq = sid & 3;
    int gp = blk * 256 + pxl;
    int y = gp >> 6, xx = gp & 63;
    *(U4*)&Pp[((size_t)b * PLANE + (size_t)(y + 1) * PW + xx + 2) * 32 + icq * 8] = *(const U4*)&lp[pxl * 32 + icq * 8];
  }
}

// ---- S = S0 + W_P * P  (rank-3 per-pixel update; replaces dense in_proj per iteration) ----
__global__ __launch_bounds__(256) void inproj_fast_kernel(const unsigned short* __restrict__ S0,
                                                          const unsigned short* __restrict__ Pp,
                                                          const float* __restrict__ ipw,
                                                          unsigned short* __restrict__ S) {
  __shared__ float wp[128][3];
  int tid = threadIdx.x;
  if (tid < 128) {
    wp[tid][0] = ipw[tid * 195 + 64];
    wp[tid][1] = ipw[tid * 195 + 65];
    wp[tid][2] = ipw[tid * 195 + 66];
  }
  __syncthreads();
  size_t e8 = (size_t)blockIdx.x * 256 + tid;   // 2,097,152
  int icq = (int)(e8 & 3), x = (int)((e8 >> 2) & 63), y = (int)((e8 >> 8) & 63);
  int cc = (int)((e8 >> 14) & 3), b = (int)(e8 >> 16);
  size_t off = (((size_t)(b * 4 + cc)) * PLANE + (size_t)(y + 1) * PW + x + 2) * 32 + icq * 8;
  uint2 p0 = *(const uint2*)&Pp[((size_t)b * PLANE + (size_t)(y + 1) * PW + x + 2) * 32];
  float h = bf2f((unsigned short)(p0.x & 0xffffu));
  float vx = bf2f((unsigned short)(p0.x >> 16));
  float vy = bf2f((unsigned short)(p0.y & 0xffffu));
  int oc0 = cc * 32 + icq * 8;
  U4 v0 = *(const U4*)&S0[off];
  unsigned a[4] = {v0.x, v0.y, v0.z, v0.w};
  unsigned out[4];
  #pragma unroll
  for (int p = 0; p < 4; ++p) {
    int o0 = oc0 + 2 * p, o1 = oc0 + 2 * p + 1;
    float r0 = bf2f((unsigned short)(a[p] & 0xffffu)) + h * wp[o0][0] + vx * wp[o0][1] + vy * wp[o0][2];
    float r1 = bf2f((unsigned short)(a[p] >> 16)) + h * wp[o1][0] + vx * wp[o1][1] + vy * wp[o1][2];
    out[p] = pack2(r0, r1);
  }
  U4 q; q.x = out[0]; q.y = out[1]; q.z = out[2]; q.w = out[3];
  *(U4*)&S[off] = q;
}

// ================= conv3x3 MFMA v6 (setprio around MFMA; GN raw-sum epilogue) =================
__global__ __launch_bounds__(512, 4) void conv3_v6(const unsigned short* __restrict__ In4,
                                                   const unsigned short* __restrict__ Wb,
                                                   const float* __restrict__ Bias,
                                                   float* __restrict__ stOut,
                                                   unsigned short* __restrict__ Out4) {
  __shared__ unsigned short lds[2][13056];
  __shared__ float sred[8][4][2];
  const int P = blockIdx.x;
  const int L = (P & 7) * 64 + (P >> 3);
  const int b = L >> 4, y0 = (L & 15) * 4;
  const int tid = threadIdx.x, l = tid & 63, w = tid >> 6;
  const int ocg = w & 1, rowg = w >> 1, l15 = l & 15, k8 = l >> 4;

  f32x4 acc[4][4];
  #pragma unroll
  for (int mf = 0; mf < 4; ++mf)
    #pragma unroll
    for (int nf = 0; nf < 4; ++nf) acc[mf][nf] = (f32x4){0.f, 0.f, 0.f, 0.f};

  auto issue_stage = [&](int cc, int nb) {
    const unsigned short* slab = In4 + (((size_t)(b * 4 + cc)) * PLANE + (size_t)y0 * PW) * 32;
    #pragma unroll
    for (int i = 0; i < 3; ++i) {
      int G = i * 512 + tid;
      int q = G >> 2;
      int r = q / 68;
      int xs = q - r * 68;
      int src = (G & ~3) | ((G & 3) ^ ((xs >> 1) & 3));
      gld16(slab + (size_t)src * 8, &lds[nb][(size_t)(i * 512 + w * 64) * 8]);
    }
    if (tid < 96) {
      int G = 1536 + tid;
      int q = G >> 2;
      int r = q / 68;
      int xs = q - r * 68;
      int src = (G & ~3) | ((G & 3) ^ ((xs >> 1) & 3));
      gld16(slab + (size_t)src * 8, &lds[nb][(size_t)(1536 + w * 64) * 8]);
    }
  };

  issue_stage(0, 0);
  __syncthreads();

  for (int cc = 0; cc < 4; ++cc) {
    const unsigned short* cur = &lds[cc & 1][0];
    if (cc < 3) issue_stage(cc + 1, (cc & 1) ^ 1);
    __builtin_amdgcn_s_setprio(1);
    #pragma unroll
    for (int t = 0; t < 9; ++t) {
      const int ky = t / 3, kx = t - ky * 3;
      bf16x8 a[4];
      #pragma unroll
      for (int mf = 0; mf < 4; ++mf)
        a[mf] = *(const bf16x8*)&Wb[(((size_t)(t * 4 + cc) * 128) + ocg * 64 + mf * 16 + l15) * 32 + k8 * 8];
      #pragma unroll
      for (int nf = 0; nf < 4; ++nf) {
        int col = nf * 16 + l15 + kx + 1;
        int slot = ((rowg + ky) * 68 + col) * 4 + (k8 ^ ((col >> 1) & 3));
        bf16x8 bv = *(const bf16x8*)&cur[(size_t)slot * 8];
        #pragma unroll
        for (int mf = 0; mf < 4; ++mf)
          acc[mf][nf] = __builtin_amdgcn_mfma_f32_16x16x32_bf16(a[mf], bv, acc[mf][nf], 0, 0, 0);
      }
    }
    __builtin_amdgcn_s_setprio(0);
    __syncthreads();
  }

  #pragma unroll
  for (int mf = 0; mf < 4; ++mf) {
    int oc = ocg * 64 + mf * 16 + k8 * 4;
    float4 bv4 = *(const float4*)&Bias[oc];
    float s = 0.f, qq = 0.f;
    #pragma unroll
    for (int nf = 0; nf < 4; ++nf) {
      float v0 = acc[mf][nf][0] + bv4.x;
      float v1 = acc[mf][nf][1] + bv4.y;
      float v2 = acc[mf][nf][2] + bv4.z;
      float v3 = acc[mf][nf][3] + bv4.w;
      s += (v0 + v1) + (v2 + v3);
      qq += (v0 * v0 + v1 * v1) + (v2 * v2 + v3 * v3);
    }
    #pragma unroll
    for (int off = 32; off > 0; off >>= 1) {
      s += __shfl_xor(s, off, 64);
      qq += __shfl_xor(qq, off, 64);
    }
    if (l == 0) { sred[w][mf][0] = s; sred[w][mf][1] = qq; }
  }
  __syncthreads();
  if (tid < 8) {
    int g = tid, og = g >> 2, mf = g & 3;
    float s = (sred[og][mf][0] + sred[og + 2][mf][0]) + (sred[og + 4][mf][0] + sred[og + 6][mf][0]);
    float qq = (sred[og][mf][1] + sred[og + 2][mf][1]) + (sred[og + 4][mf][1] + sred[og + 6][mf][1]);
    atomicAdd(&stOut[(b * 8 + g) * 2], s);
    atomicAdd(&stOut[(b * 8 + g) * 2 + 1], qq);
  }

  unsigned short* eb = &lds[0][0];
  #pragma unroll
  for (int h = 0; h < 2; ++h) {
    if ((rowg >> 1) == h) {
      int prow = rowg & 1;
      #pragma unroll
      for (int mf = 0; mf < 4; ++mf) {
        int oc = ocg * 64 + mf * 16 + k8 * 4;
        float4 bv4 = *(const float4*)&Bias[oc];
        #pragma unroll
        for (int nf = 0; nf < 4; ++nf) {
          int pxl = prow * 64 + nf * 16 + l15;
          unsigned lo = pack2(acc[mf][nf][0] + bv4.x, acc[mf][nf][1] + bv4.y);
          unsigned hi = pack2(acc[mf][nf][2] + bv4.z, acc[mf][nf][3] + bv4.w);
          unsigned off = (unsigned)(pxl * 256 + oc * 2) ^ ((pxl & 7) << 4);
          *(uint2*)((char*)eb + off) = make_uint2(lo, hi);
        }
      }
    }
    __syncthreads();
    {
      int pxl = tid >> 2, icq = tid & 3;
      int px = h * 128 + pxl;
      int yy = px >> 6, xx = px & 63;
      #pragma unroll
      for (int cc2 = 0; cc2 < 4; ++cc2) {
        unsigned off = (unsigned)(pxl * 256 + cc2 * 64 + icq * 16) ^ ((pxl & 7) << 4);
        U4 q = *(const U4*)((char*)eb + off);
        *(U4*)&Out4[(((size_t)(b * 4 + cc2)) * PLANE + (size_t)(y0 + yy + 1) * PW + xx + 2) * 32 + icq * 8] = q;
      }
    }
    __syncthreads();
  }
}

// ---- 1x1 conv via MFMA (used once for S0 precompute) ----
__global__ __launch_bounds__(256, 2) void conv1_v2(const unsigned short* __restrict__ srcA, int ncA,
                                                   const unsigned short* __restrict__ srcB, int nc,
                                                   const unsigned short* __restrict__ Wb,
                                                   const float* __restrict__ Bias, int perB,
                                                   unsigned short* __restrict__ Out4) {
  __shared__ unsigned short lds[32768];
  const int P = blockIdx.x;
  const int L = (P & 7) * 64 + (P >> 3);
  const int b = L >> 4, px0 = (L & 15) * 256;
  const int tid = threadIdx.x, l = tid & 63, w = tid >> 6;
  const int ocg = w & 1, rowg = w >> 1, l15 = l & 15, k8 = l >> 4;

  f32x4 acc[4][8];
  #pragma unroll
  for (int mf = 0; mf < 4; ++mf)
    #pragma unroll
    for (int nf = 0; nf < 8; ++nf) acc[mf][nf] = (f32x4){0.f, 0.f, 0.f, 0.f};

  for (int cc = 0; cc < nc; ++cc) {
    const unsigned short* base = (cc < ncA) ? srcA + ((size_t)(b * ncA + cc)) * PLANE * 32
                                            : srcB + ((size_t)b) * PLANE * 32;
    bf16x8 a[4];
    #pragma unroll
    for (int mf = 0; mf < 4; ++mf)
      a[mf] = *(const bf16x8*)&Wb[(((size_t)cc * 128) + ocg * 64 + mf * 16 + l15) * 32 + k8 * 8];
    #pragma unroll
    for (int nf = 0; nf < 8; ++nf) {
      int px = px0 + rowg * 128 + nf * 16 + l15;
      int y = px >> 6, x = px & 63;
      bf16x8 bv = *(const bf16x8*)&base[((size_t)(y + 1) * PW + x + 2) * 32 + k8 * 8];
      #pragma unroll
      for (int mf = 0; mf < 4; ++mf)
        acc[mf][nf] = __builtin_amdgcn_mfma_f32_16x16x32_bf16(a[mf], bv, acc[mf][nf], 0, 0, 0);
    }
  }
  const float* bp = Bias + (perB ? b * 128 : 0);
  #pragma unroll
  for (int mf = 0; mf < 4; ++mf) {
    int oc = ocg * 64 + mf * 16 + k8 * 4;
    float4 bv4 = *(const float4*)&bp[oc];
    #pragma unroll
    for (int nf = 0; nf < 8; ++nf) {
      int pxl = rowg * 128 + nf * 16 + l15;
      unsigned lo = pack2(acc[mf][nf][0] + bv4.x, acc[mf][nf][1] + bv4.y);
      unsigned hi = pack2(acc[mf][nf][2] + bv4.z, acc[mf][nf][3] + bv4.w);
      unsigned off = (unsigned)(pxl * 256 + oc * 2) ^ ((pxl & 7) << 4);
      *(uint2*)((char*)lds + off) = make_uint2(lo, hi);
    }
  }
  __syncthreads();
  #pragma unroll
  for (int cc2 = 0; cc2 < 4; ++cc2)
    #pragma unroll
    for (int it = 0; it < 4; ++it) {
      int sid = it * 256 + tid;
      int pxl = sid >> 2, icq = sid & 3;
      unsigned off = (unsigned)(pxl * 256 + cc2 * 64 + icq * 16) ^ ((pxl & 7) << 4);
      U4 q = *(const U4*)((char*)lds + off);
      int px = px0 + pxl;
      int yy = px >> 6, xx = px & 63;
      *(U4*)&Out4[(((size_t)(b * 4 + cc2)) * PLANE + (size_t)(yy + 1) * PW + xx + 2) * 32 + icq * 8] = q;
    }
}

// ---- A = silu(gn1(A)) in-place; mu/ri from raw sums ----
__global__ __launch_bounds__(256) void gn1apply_kernel(unsigned short* __restrict__ A,
                                                       const float* __restrict__ st, const float* __restrict__ gam,
                                                       const float* __restrict__ bet) {
  size_t e8 = (size_t)blockIdx.x * 256 + threadIdx.x;
  int icq = (int)(e8 & 3), x = (int)((e8 >> 2) & 63), y = (int)((e8 >> 8) & 63);
  int cc = (int)((e8 >> 14) & 3), b = (int)(e8 >> 16);
  size_t off = (((size_t)(b * 4 + cc)) * PLANE + (size_t)(y + 1) * PW + x + 2) * 32 + icq * 8;
  int ch = icq * 8;
  int g = cc * 2 + (ch >> 4);
  const float invn = 1.f / 65536.f;
  float ssum = st[(b * 8 + g) * 2], qsum = st[(b * 8 + g) * 2 + 1];
  float mu = ssum * invn;
  float ri = rsqrtf(qsum * invn - mu * mu + 1e-5f);
  int c0 = cc * 32 + ch;
  float4 g0 = *(const float4*)&gam[c0], g1 = *(const float4*)&gam[c0 + 4];
  float4 b0 = *(const float4*)&bet[c0], b1 = *(const float4*)&bet[c0 + 4];
  float gv[8] = {g0.x, g0.y, g0.z, g0.w, g1.x, g1.y, g1.z, g1.w};
  float bv[8] = {b0.x, b0.y, b0.z, b0.w, b1.x, b1.y, b1.z, b1.w};
  U4 va = *(const U4*)&A[off];
  unsigned aa[4] = {va.x, va.y, va.z, va.w};
  unsigned out[4];
  #pragma unroll
  for (int p = 0; p < 4; ++p) {
    float h0 = (bf2f((unsigned short)(aa[p] & 0xffffu)) - mu) * ri * gv[2 * p] + bv[2 * p];
    float h1 = (bf2f((unsigned short)(aa[p] >> 16)) - mu) * ri * gv[2 * p + 1] + bv[2 * p + 1];
    out[p] = pack2(silu_f(h0), silu_f(h1));
  }
  U4 q; q.x = out[0]; q.y = out[1]; q.z = out[2]; q.w = out[3];
  *(U4*)&A[off] = q;
}

// ---- S = silu(S + gn2(Bb)); mu/ri from raw sums ----
__global__ __launch_bounds__(256) void gn2add4_kernel(unsigned short* __restrict__ S, const unsigned short* __restrict__ Bb,
                                                      const float* __restrict__ st, const float* __restrict__ gam,
                                                      const float* __restrict__ bet) {
  size_t e8 = (size_t)blockIdx.x * 256 + threadIdx.x;
  int icq = (int)(e8 & 3), x = (int)((e8 >> 2) & 63), y = (int)((e8 >> 8) & 63);
  int cc = (int)((e8 >> 14) & 3), b = (int)(e8 >> 16);
  size_t off = (((size_t)(b * 4 + cc)) * PLANE + (size_t)(y + 1) * PW + x + 2) * 32 + icq * 8;
  int ch = icq * 8;
  int g = cc * 2 + (ch >> 4);
  const float invn = 1.f / 65536.f;
  float ssum = st[(b * 8 + g) * 2], qsum = st[(b * 8 + g) * 2 + 1];
  float mu = ssum * invn;
  float ri = rsqrtf(qsum * invn - mu * mu + 1e-5f);
  int c0 = cc * 32 + ch;
  float4 g0 = *(const float4*)&gam[c0], g1 = *(const float4*)&gam[c0 + 4];
  float4 b0 = *(const float4*)&bet[c0], b1 = *(const float4*)&bet[c0 + 4];
  float gv[8] = {g0.x, g0.y, g0.z, g0.w, g1.x, g1.y, g1.z, g1.w};
  float bv[8] = {b0.x, b0.y, b0.z, b0.w, b1.x, b1.y, b1.z, b1.w};
  U4 vb = *(const U4*)&Bb[off];
  U4 vs = *(const U4*)&S[off];
  unsigned ab[4] = {vb.x, vb.y, vb.z, vb.w};
  unsigned as[4] = {vs.x, vs.y, vs.z, vs.w};
  unsigned out[4];
  #pragma unroll
  for (int p = 0; p < 4; ++p) {
    float h0 = (bf2f((unsigned short)(ab[p] & 0xffffu)) - mu) * ri * gv[2 * p] + bv[2 * p];
    float h1 = (bf2f((unsigned short)(ab[p] >> 16)) - mu) * ri * gv[2 * p + 1] + bv[2 * p + 1];
    float r0 = silu_f(bf2f((unsigned short)(as[p] & 0xffffu)) + h0);
    float r1 = silu_f(bf2f((unsigned short)(as[p] >> 16)) + h1);
    out[p] = pack2(r0, r1);
  }
  U4 q; q.x = out[0]; q.y = out[1]; q.z = out[2]; q.w = out[3];
  *(U4*)&S[off] = q;
}

// ---- fused grid_sample + out_proj: rd[t][oc] = ob[oc] + sum_ic wo[oc][ic] * bilerp(S)[t][ic] ----
__global__ __launch_bounds__(256) void gsample_op_kernel(const unsigned short* __restrict__ S4,
                                                         const float* __restrict__ x,
                                                         const unsigned short* __restrict__ wo,
                                                         const float* __restrict__ ob,
                                                         float* __restrict__ rd) {
  __shared__ float sv[2][128];
  int tid = threadIdx.x;
  int tt = tid >> 7, c = tid & 127;
  int token = blockIdx.x * 2 + tt;
  int b = token >> 8;
  // phase 1: gather bilerp of channel c
  {
    float cx = x[token * 2], cy = x[token * 2 + 1];
    float fx = (cx + 1.f) * 32.f - 0.5f;
    float fy = (cy + 1.f) * 32.f - 0.5f;
    float x0f = floorf(fx), y0f = floorf(fy);
    float wx = fx - x0f, wy = fy - y0f;
    const unsigned short* Sb = S4 + ((size_t)(b * 4 + (c >> 5)) * PLANE) * 32 + (c & 31);
    float acc = 0.f;
    #pragma unroll
    for (int cor = 0; cor < 4; ++cor) {
      float xi = x0f + (float)(cor & 1), yi = y0f + (float)(cor >> 1);
      float wgt = ((cor & 1) ? wx : 1.f - wx) * ((cor >> 1) ? wy : 1.f - wy);
      if (xi >= 0.f && xi <= 63.f && yi >= 0.f && yi <= 63.f)
        acc += bf2f(Sb[(size_t)(((int)yi + 1) * PW + (int)xi + 2) * 32]) * wgt;
    }
    sv[tt][c] = acc;
  }
  __syncthreads();
  // phase 2: per-token 128x128 projection (thread = oc)
  {
    int oc = c;
    float acc = ob[oc];
    #pragma unroll
    for (int cc = 0; cc < 4; ++cc) {
      #pragma unroll
      for (int q8 = 0; q8 < 4; ++q8) {
        U4 wq = *(const U4*)&wo[(size_t)cc * 4096 + oc * 32 + q8 * 8];
        unsigned a[4] = {wq.x, wq.y, wq.z, wq.w};
        const float* sp = &sv[tt][cc * 32 + q8 * 8];
        #pragma unroll
        for (int p = 0; p < 4; ++p) {
          acc += bf2f((unsigned short)(a[p] & 0xffffu)) * sp[2 * p];
          acc += bf2f((unsigned short)(a[p] >> 16)) * sp[2 * p + 1];
        }
      }
    }
    rd[(size_t)token * 128 + oc] = acc;
  }
}

__global__ __launch_bounds__(256) void mlp_fc_kernel(const float* __restrict__ in, const float* __restrict__ w,
                                                     const float* __restrict__ init, int initPerB,
                                                     float* __restrict__ out) {
  int tok0 = blockIdx.x * 2;
  int tid = threadIdx.x;
  __shared__ float sr[2][128];
  sr[tid >> 7][tid & 127] = in[(size_t)tok0 * 128 + tid];
  __syncthreads();
  int t = tid >> 7, j = tid & 127;
  int token = tok0 + t;
  int b = token >> 8;
  float acc = initPerB ? init[b * 128 + j] : init[j];
  #pragma unroll 8
  for (int k = 0; k < 128; ++k) acc += sr[t][k] * w[(size_t)k * 128 + j];
  out[(size_t)token * 128 + j] = silu_f(acc);
}

__global__ __launch_bounds__(256) void mlp3_update_kernel(const float* __restrict__ h2, const float* __restrict__ w3,
                                                          const float* __restrict__ b3, float* __restrict__ x) {
  int token = blockIdx.x * 256 + threadIdx.x;
  if (token >= BN * TN) return;
  float d0 = b3[0], d1 = b3[1];
  const float* h = h2 + (size_t)token * 128;
  #pragma unroll 8
  for (int k = 0; k < 128; ++k) { float hv = h[k]; d0 += hv * w3[k * 2]; d1 += hv * w3[k * 2 + 1]; }
  float nx = x[token * 2] + 0.2f * d0;
  float ny = x[token * 2 + 1] + 0.2f * d1;
  x[token * 2] = fminf(fmaxf(nx, -1.f), 1.f);
  x[token * 2 + 1] = fminf(fmaxf(ny, -1.f), 1.f);
}

extern "C" void kernel_launch(void* const* d_in, const int* in_sizes, int n_in,
                              void* d_out, int out_size, void* d_ws, size_t ws_size,
                              hipStream_t stream) {
  const float* M   = (const float*)d_in[0];
  const float* x0  = (const float*)d_in[1];
  const float* te  = (const float*)d_in[2];
  const float* ipw = (const float*)d_in[3];
  const float* ipb = (const float*)d_in[4];
  const float* c1w = (const float*)d_in[5];
  const float* c1b = (const float*)d_in[6];
  const float* g1w = (const float*)d_in[7];
  const float* g1b = (const float*)d_in[8];
  const float* c2w = (const float*)d_in[9];
  const float* c2b = (const float*)d_in[10];
  const float* g2w = (const float*)d_in[11];
  const float* g2b = (const float*)d_in[12];
  const float* ow  = (const float*)d_in[13];
  const float* ob  = (const float*)d_in[14];
  const float* w1  = (const float*)d_in[15];
  const float* b1  = (const float*)d_in[16];
  const float* w2  = (const float*)d_in[17];
  const float* b2  = (const float*)d_in[18];
  const float* w3  = (const float*)d_in[19];
  const float* b3  = (const float*)d_in[20];

  const size_t PSH = (size_t)PLANE * 32;
  float* f     = (float*)d_ws;
  float* wx    = f;
  float* tctr  = wx + 16384;
  float* tpart = tctr + 4096;
  float* stats = tpart + 4096;     // 18 slices x 512 raw sums
  float* rd    = stats + 9216;
  float* h1    = rd + 1048576;
  float* h2    = h1 + 1048576;
  unsigned short* S4  = (unsigned short*)(h2 + 1048576);
  unsigned short* A4  = S4 + 128 * PSH;
  unsigned short* B4  = A4 + 128 * PSH;
  unsigned short* S0  = B4 + 128 * PSH;
  unsigned short* Ms4 = S0 + 128 * PSH;
  unsigned short* Pp  = Ms4 + 64 * PSH;
  unsigned short* wc  = Pp + 32 * PSH;
  unsigned short* wi  = wc + 884736;
  unsigned short* wo  = wi + 12288;

  copy_kernel<<<64, 256, 0, stream>>>(x0, wx, 16384);
  zstats_kernel<<<36, 256, 0, stream>>>(stats);
  zerohalo_kernel<<<2352, 256, 0, stream>>>(S4);   // S4,A4,B4 halos
  resize_t_kernel<<<dim3(16, 32), 256, 0, stream>>>(M, Ms4);
  tctr_kernel<<<16, 256, 0, stream>>>(ipw, ipb, te, tctr);
  tpart_kernel<<<16, 256, 0, stream>>>(w1, b1, te, tpart);
  for (int i = 0; i < 3; ++i) {
    wprep_kernel<<<576, 256, 0, stream>>>(c1w + (size_t)i * 147456, wc + (size_t)(2 * i) * 147456);
    wprep_kernel<<<576, 256, 0, stream>>>(c2w + (size_t)i * 147456, wc + (size_t)(2 * i + 1) * 147456);
  }
  wprep_in_kernel<<<48, 256, 0, stream>>>(ipw, wi);
  wprep_out_kernel<<<64, 256, 0, stream>>>(ow, wo);
  // S0 = W_Ms * Ms + tctr  (loop-invariant part of in_proj, computed once)
  conv1_v2<<<512, 256, 0, stream>>>(Ms4, 2, nullptr, 2, wi, tctr, 1, S0);

  for (int r = 0; r < 3; ++r) {
    raster4_kernel<<<dim3(16, 32), 256, 0, stream>>>(wx, Pp);
    inproj_fast_kernel<<<8192, 256, 0, stream>>>(S0, Pp, ipw, S4);
    for (int i = 0; i < 3; ++i) {
      float* stA = stats + (size_t)(r * 3 + i) * 512;
      float* stB = stats + (size_t)(9 + r * 3 + i) * 512;
      conv3_v6<<<512, 512, 0, stream>>>(S4, wc + (size_t)(2 * i) * 147456, c1b + i * 128, stA, A4);
      gn1apply_kernel<<<8192, 256, 0, stream>>>(A4, stA, g1w + i * 128, g1b + i * 128);
      conv3_v6<<<512, 512, 0, stream>>>(A4, wc + (size_t)(2 * i + 1) * 147456, c2b + i * 128, stB, B4);
      gn2add4_kernel<<<8192, 256, 0, stream>>>(S4, B4, stB, g2w + i * 128, g2b + i * 128);
    }
    gsample_op_kernel<<<4096, 256, 0, stream>>>(S4, wx, wo, ob, rd);
    mlp_fc_kernel<<<4096, 256, 0, stream>>>(rd, w1, tpart, 1, h1);
    mlp_fc_kernel<<<4096, 256, 0, stream>>>(h1, w2, b2, 0, h2);
    mlp3_update_kernel<<<32, 256, 0, stream>>>(h2, w3, b3, wx);
  }
  copy_kernel<<<64, 256, 0, stream>>>(wx, (float*)d_out, 16384);
}

// Round 16
// 1676.519 us; speedup vs baseline: 1.0306x; 1.0306x over previous
//
#include <hip/hip_runtime.h>
#include <cstddef>

#define BN 32
#define TN 256
#define PW 68
#define PLANE 4488   // 66 rows x 68 px; interior rows 1..64, cols 2..65

typedef __attribute__((ext_vector_type(8))) short bf16x8;
typedef __attribute__((ext_vector_type(4))) float f32x4;

struct __attribute__((aligned(16))) U4 { unsigned x, y, z, w; };

__device__ __forceinline__ float silu_f(float v) { return v / (1.f + __expf(-v)); }

__device__ __forceinline__ unsigned short f2bf(float f) {
  unsigned u = __float_as_uint(f);
  unsigned r = (u + 0x7fffu + ((u >> 16) & 1u)) >> 16;
  return (unsigned short)r;
}
__device__ __forceinline__ float bf2f(unsigned short h) {
  return __uint_as_float((unsigned)h << 16);
}
__device__ __forceinline__ unsigned pack2(float a, float b) {
  return (unsigned)f2bf(a) | ((unsigned)f2bf(b) << 16);
}

// async 16B global->LDS; lds dest = wave-uniform base + lane*16
__device__ __forceinline__ void gld16(const unsigned short* g, unsigned short* l) {
  __builtin_amdgcn_global_load_lds((const __attribute__((address_space(1))) unsigned int*)g,
                                   (__attribute__((address_space(3))) unsigned int*)l, 16, 0, 0);
}

__global__ __launch_bounds__(256) void copy_kernel(const float* __restrict__ src, float* __restrict__ dst, int n) {
  int i = blockIdx.x * 256 + threadIdx.x;
  if (i < n) dst[i] = src[i];
}

__global__ __launch_bounds__(256) void zstats_kernel(float* __restrict__ s) {
  int i = blockIdx.x * 256 + threadIdx.x;
  if (i < 18 * 512) s[i] = 0.f;
}

// ---- zero the halo ring of S4/A4/B4 (384 contiguous planes); halo = rows 0,65 + cols 0,1,66,67 ----
__global__ __launch_bounds__(256) void zerohalo_kernel(unsigned short* __restrict__ base) {
  int idx = blockIdx.x * 256 + threadIdx.x;
  if (idx >= 384 * 1568) return;
  int p = idx / 1568, rem = idx % 1568;
  int hp = rem >> 2, icq = rem & 3;
  int row, x;
  if (hp < 68) { row = 0; x = hp; }
  else if (hp < 136) { row = 65; x = hp - 68; }
  else {
    int i = hp - 136;
    row = 1 + (i >> 2);
    const int cols[4] = {0, 1, 66, 67};
    x = cols[i & 3];
  }
  U4 z = {0u, 0u, 0u, 0u};
  *(U4*)&base[((size_t)p * PLANE + row * PW + x) * 32 + icq * 8] = z;
}

// ---- resize 128->64 (exact 2x2 avg) -> padded [b][2cc][66][68][32] bf16 ----
__global__ __launch_bounds__(256) void resize_t_kernel(const float* __restrict__ M, unsigned short* __restrict__ Ms4) {
  __shared__ unsigned short lt[4 * 64 * 72];
  int b = blockIdx.y, yt = blockIdx.x;
  int tid = threadIdx.x;
  for (int i = tid; i < 4 * 64 * 64; i += 256) {
    int c = i >> 8, y = (i >> 6) & 3, x = i & 63;
    const float* p = M + (((size_t)(b * 64 + c) * 128) + (yt * 4 + y) * 2) * 128 + 2 * x;
    float2 a = *(const float2*)p;
    float2 bq = *(const float2*)(p + 128);
    lt[(y * 64 + x) * 72 + c] = f2bf(0.25f * (a.x + a.y + bq.x + bq.y));
  }
  __syncthreads();
  for (int i = tid; i < 2048; i += 256) {
    int icq = i & 3, pxl = (i >> 2) & 255, cc = i >> 10;
    U4 q = *(const U4*)&lt[pxl * 72 + cc * 32 + icq * 8];
    int y = yt * 4 + (pxl >> 6), x = pxl & 63;
    *(U4*)&Ms4[(((size_t)(b * 2 + cc) * PLANE) + (size_t)(y + 1) * PW + x + 2) * 32 + icq * 8] = q;
  }
}

// ---- conv weight prep: W[oc][ic][3][3] fp32 -> [tap*4+cc][128 oc][32 ic] bf16 ----
__global__ __launch_bounds__(256) void wprep_kernel(const float* __restrict__ Wsrc, unsigned short* __restrict__ Wdst) {
  int idx = blockIdx.x * 256 + threadIdx.x;
  if (idx >= 147456) return;
  int icp = idx & 31;
  int oc = (idx >> 5) & 127;
  int tc = idx >> 12;
  int t = tc >> 2, cch = tc & 3;
  Wdst[idx] = f2bf(Wsrc[(size_t)oc * 1152 + (size_t)(cch * 32 + icp) * 9 + t]);
}

__global__ __launch_bounds__(256) void wprep_in_kernel(const float* __restrict__ ipw, unsigned short* __restrict__ wi) {
  int idx = blockIdx.x * 256 + threadIdx.x;
  if (idx >= 12288) return;
  int icp = idx & 31, oc = (idx >> 5) & 127, cc = idx >> 12;
  float f = 0.f;
  if (cc < 2) f = ipw[oc * 195 + cc * 32 + icp];
  else if (icp < 3) f = ipw[oc * 195 + 64 + icp];
  wi[idx] = f2bf(f);
}

__global__ __launch_bounds__(256) void wprep_out_kernel(const float* __restrict__ ow, unsigned short* __restrict__ wo) {
  int idx = blockIdx.x * 256 + threadIdx.x;
  if (idx >= 16384) return;
  int icp = idx & 31, oc = (idx >> 5) & 127, cc = idx >> 12;
  wo[idx] = f2bf(ow[oc * 128 + cc * 32 + icp]);
}

__global__ __launch_bounds__(256) void tctr_kernel(const float* __restrict__ w, const float* __restrict__ bias,
                                                   const float* __restrict__ te, float* __restrict__ tctr) {
  int i = blockIdx.x * 256 + threadIdx.x;
  if (i >= BN * 128) return;
  int b = i >> 7, o = i & 127;
  float acc = bias[o];
  const float* wp = w + (size_t)o * 195 + 67;
  const float* t = te + b * 128;
  #pragma unroll 8
  for (int k = 0; k < 128; ++k) acc += wp[k] * t[k];
  tctr[i] = acc;
}

__global__ __launch_bounds__(256) void tpart_kernel(const float* __restrict__ w1, const float* __restrict__ b1,
                                                    const float* __restrict__ te, float* __restrict__ tp) {
  int i = blockIdx.x * 256 + threadIdx.x;
  if (i >= BN * 128) return;
  int b = i >> 7, j = i & 127;
  float acc = b1[j];
  #pragma unroll 8
  for (int k = 0; k < 128; ++k) acc += te[b * 128 + k] * w1[(size_t)(128 + k) * 128 + j];
  tp[i] = acc;
}

// ---- rasterize -> padded Pp [b][66][68][32] bf16 (ch0=heat,1=vx,2=vy, rest 0) ----
__global__ __launch_bounds__(256) void raster4_kernel(const float* __restrict__ x, unsigned short* __restrict__ Pp) {
  int b = blockIdx.y, blk = blockIdx.x;
  int tid = threadIdx.x;
  int pix = blk * 256 + tid;
  __shared__ float spx[TN], spy[TN];
  __shared__ unsigned short lp[256 * 32];
  spx[tid] = (x[(b * TN + tid) * 2] + 1.f) * 0.5f * 63.f;
  spy[tid] = (x[(b * TN + tid) * 2 + 1] + 1.f) * 0.5f * 63.f;
  __syncthreads();
  float fx = (float)(pix & 63), fy = (float)(pix >> 6);
  const float coef = -0.5f / (1.44f + 1e-8f);
  float heat = 0.f, sx = 0.f, sy = 0.f, sw = 0.f;
  float prevx = 0.f, prevy = 0.f;
  for (int t = 0; t < TN; ++t) {
    float px = spx[t], py = spy[t];
    float ddx = px - fx, ddy = py - fy;
    float w = __expf(coef * (ddx * ddx + ddy * ddy));
    heat = fmaxf(heat, w);
    float vx = (t == 0) ? 0.f : px - prevx;
    float vy = (t == 0) ? 0.f : py - prevy;
    prevx = px; prevy = py;
    sx += w * vx; sy += w * vy; sw += w;
  }
  float inv = 1.f / fmaxf(sw, 1e-6f);
  U4 q0; q0.x = pack2(heat, sx * inv); q0.y = pack2(sy * inv, 0.f); q0.z = 0u; q0.w = 0u;
  U4 z = {0u, 0u, 0u, 0u};
  *(U4*)&lp[tid * 32 + 0] = q0;
  *(U4*)&lp[tid * 32 + 8] = z;
  *(U4*)&lp[tid * 32 + 16] = z;
  *(U4*)&lp[tid * 32 + 24] = z;
  __syncthreads();
  for (int it = 0; it < 4; ++it) {
    int sid = it * 256 + tid;
    int pxl = sid >> 2, icq = sid & 3;
    int gp = blk * 256 + pxl;
    int y = gp >> 6, xx = gp & 63;
    *(U4*)&Pp[((size_t)b * PLANE + (size_t)(y + 1) * PW + xx + 2) * 32 + icq * 8] = *(const U4*)&lp[pxl * 32 + icq * 8];
  }
}

// ---- S = S0 + W_P * P  (rank-3 per-pixel update; replaces dense in_proj per iteration) ----
__global__ __launch_bounds__(256) void inproj_fast_kernel(const unsigned short* __restrict__ S0,
                                                          const unsigned short* __restrict__ Pp,
                                                          const float* __restrict__ ipw,
                                                          unsigned short* __restrict__ S) {
  __shared__ float wp[128][3];
  int tid = threadIdx.x;
  if (tid < 128) {
    wp[tid][0] = ipw[tid * 195 + 64];
    wp[tid][1] = ipw[tid * 195 + 65];
    wp[tid][2] = ipw[tid * 195 + 66];
  }
  __syncthreads();
  size_t e8 = (size_t)blockIdx.x * 256 + tid;   // 2,097,152
  int icq = (int)(e8 & 3), x = (int)((e8 >> 2) & 63), y = (int)((e8 >> 8) & 63);
  int cc = (int)((e8 >> 14) & 3), b = (int)(e8 >> 16);
  size_t off = (((size_t)(b * 4 + cc)) * PLANE + (size_t)(y + 1) * PW + x + 2) * 32 + icq * 8;
  uint2 p0 = *(const uint2*)&Pp[((size_t)b * PLANE + (size_t)(y + 1) * PW + x + 2) * 32];
  float h = bf2f((unsigned short)(p0.x & 0xffffu));
  float vx = bf2f((unsigned short)(p0.x >> 16));
  float vy = bf2f((unsigned short)(p0.y & 0xffffu));
  int oc0 = cc * 32 + icq * 8;
  U4 v0 = *(const U4*)&S0[off];
  unsigned a[4] = {v0.x, v0.y, v0.z, v0.w};
  unsigned out[4];
  #pragma unroll
  for (int p = 0; p < 4; ++p) {
    int o0 = oc0 + 2 * p, o1 = oc0 + 2 * p + 1;
    float r0 = bf2f((unsigned short)(a[p] & 0xffffu)) + h * wp[o0][0] + vx * wp[o0][1] + vy * wp[o0][2];
    float r1 = bf2f((unsigned short)(a[p] >> 16)) + h * wp[o1][0] + vx * wp[o1][1] + vy * wp[o1][2];
    out[p] = pack2(r0, r1);
  }
  U4 q; q.x = out[0]; q.y = out[1]; q.z = out[2]; q.w = out[3];
  *(U4*)&S[off] = q;
}

// ================= conv3x3 MFMA v8: 3-slab pipeline, counted vmcnt (never 0 mid-loop) =================
// T3/T4 pattern: issue chunk cc+2 before consuming cc; raw s_barrier with vmcnt(3) so the next
// stage's DMAs stay in flight across the barrier. LDS 3x26.1KB; residency already reg-capped at
// 2 blocks/CU (128 combined VGPR+AGPR) so no occupancy change vs 2-slab.
__global__ __launch_bounds__(512, 4) void conv3_v8(const unsigned short* __restrict__ In4,
                                                   const unsigned short* __restrict__ Wb,
                                                   const float* __restrict__ Bias,
                                                   float* __restrict__ stOut,
                                                   unsigned short* __restrict__ Out4) {
  __shared__ unsigned short lds[3][13056];
  __shared__ float sred[8][4][2];
  const int P = blockIdx.x;
  const int L = (P & 7) * 64 + (P >> 3);
  const int b = L >> 4, y0 = (L & 15) * 4;
  const int tid = threadIdx.x, l = tid & 63, w = tid >> 6;
  const int ocg = w & 1, rowg = w >> 1, l15 = l & 15, k8 = l >> 4;

  f32x4 acc[4][4];
  #pragma unroll
  for (int mf = 0; mf < 4; ++mf)
    #pragma unroll
    for (int nf = 0; nf < 4; ++nf) acc[mf][nf] = (f32x4){0.f, 0.f, 0.f, 0.f};

  auto issue_stage = [&](int cc, int nb) {   // pre-swizzled global source -> linear LDS (1632 granules)
    const unsigned short* slab = In4 + (((size_t)(b * 4 + cc)) * PLANE + (size_t)y0 * PW) * 32;
    #pragma unroll
    for (int i = 0; i < 3; ++i) {
      int G = i * 512 + tid;
      int q = G >> 2;
      int r = q / 68;
      int xs = q - r * 68;
      int src = (G & ~3) | ((G & 3) ^ ((xs >> 1) & 3));
      gld16(slab + (size_t)src * 8, &lds[nb][(size_t)(i * 512 + w * 64) * 8]);
    }
    if (tid < 96) {
      int G = 1536 + tid;
      int q = G >> 2;
      int r = q / 68;
      int xs = q - r * 68;
      int src = (G & ~3) | ((G & 3) ^ ((xs >> 1) & 3));
      gld16(slab + (size_t)src * 8, &lds[nb][(size_t)(1536 + w * 64) * 8]);
    }
  };

  issue_stage(0, 0);
  issue_stage(1, 1);

  for (int cc = 0; cc < 4; ++cc) {
    // wait for chunk cc's DMA; keep next stage's loads (<=4/wave) in flight. vmcnt(3) is safe
    // for both 3- and 4-op waves (waits at most one extra op). Last iter drains fully.
    if (cc == 3) {
      asm volatile("s_waitcnt vmcnt(0)" ::: "memory");
    } else {
      asm volatile("s_waitcnt vmcnt(3)" ::: "memory");
    }
    __builtin_amdgcn_s_barrier();
    if (cc < 2) issue_stage(cc + 2, cc + 2);   // chunk2->slot2, chunk3->slot0 (slot0 free: read at cc=0)
    const unsigned short* cur = &lds[cc == 3 ? 0 : cc][0];
    __builtin_amdgcn_s_setprio(1);
    #pragma unroll
    for (int t = 0; t < 9; ++t) {
      const int ky = t / 3, kx = t - ky * 3;
      bf16x8 a[4];
      #pragma unroll
      for (int mf = 0; mf < 4; ++mf)
        a[mf] = *(const bf16x8*)&Wb[(((size_t)(t * 4 + cc) * 128) + ocg * 64 + mf * 16 + l15) * 32 + k8 * 8];
      #pragma unroll
      for (int nf = 0; nf < 4; ++nf) {
        int col = nf * 16 + l15 + kx + 1;
        int slot = ((rowg + ky) * 68 + col) * 4 + (k8 ^ ((col >> 1) & 3));
        bf16x8 bv = *(const bf16x8*)&cur[(size_t)slot * 8];
        #pragma unroll
        for (int mf = 0; mf < 4; ++mf)
          acc[mf][nf] = __builtin_amdgcn_mfma_f32_16x16x32_bf16(a[mf], bv, acc[mf][nf], 0, 0, 0);
      }
    }
    __builtin_amdgcn_s_setprio(0);
  }

  // ---- GN raw-sum accumulation (conv output incl bias); group g = oc/16 = ocg*4+mf ----
  #pragma unroll
  for (int mf = 0; mf < 4; ++mf) {
    int oc = ocg * 64 + mf * 16 + k8 * 4;
    float4 bv4 = *(const float4*)&Bias[oc];
    float s = 0.f, qq = 0.f;
    #pragma unroll
    for (int nf = 0; nf < 4; ++nf) {
      float v0 = acc[mf][nf][0] + bv4.x;
      float v1 = acc[mf][nf][1] + bv4.y;
      float v2 = acc[mf][nf][2] + bv4.z;
      float v3 = acc[mf][nf][3] + bv4.w;
      s += (v0 + v1) + (v2 + v3);
      qq += (v0 * v0 + v1 * v1) + (v2 * v2 + v3 * v3);
    }
    #pragma unroll
    for (int off = 32; off > 0; off >>= 1) {
      s += __shfl_xor(s, off, 64);
      qq += __shfl_xor(qq, off, 64);
    }
    if (l == 0) { sred[w][mf][0] = s; sred[w][mf][1] = qq; }
  }
  __syncthreads();
  if (tid < 8) {
    int g = tid, og = g >> 2, mf = g & 3;
    float s = (sred[og][mf][0] + sred[og + 2][mf][0]) + (sred[og + 4][mf][0] + sred[og + 6][mf][0]);
    float qq = (sred[og][mf][1] + sred[og + 2][mf][1]) + (sred[og + 4][mf][1] + sred[og + 6][mf][1]);
    atomicAdd(&stOut[(b * 8 + g) * 2], s);
    atomicAdd(&stOut[(b * 8 + g) * 2 + 1], qq);
  }

  // epilogue: two 128-px halves through 32 KB LDS repack (XOR swz), coalesced 128B-aligned writes
  unsigned short* eb = &lds[0][0];
  #pragma unroll
  for (int h = 0; h < 2; ++h) {
    if ((rowg >> 1) == h) {
      int prow = rowg & 1;
      #pragma unroll
      for (int mf = 0; mf < 4; ++mf) {
        int oc = ocg * 64 + mf * 16 + k8 * 4;
        float4 bv4 = *(const float4*)&Bias[oc];
        #pragma unroll
        for (int nf = 0; nf < 4; ++nf) {
          int pxl = prow * 64 + nf * 16 + l15;
          unsigned lo = pack2(acc[mf][nf][0] + bv4.x, acc[mf][nf][1] + bv4.y);
          unsigned hi = pack2(acc[mf][nf][2] + bv4.z, acc[mf][nf][3] + bv4.w);
          unsigned off = (unsigned)(pxl * 256 + oc * 2) ^ ((pxl & 7) << 4);
          *(uint2*)((char*)eb + off) = make_uint2(lo, hi);
        }
      }
    }
    __syncthreads();
    {
      int pxl = tid >> 2, icq = tid & 3;
      int px = h * 128 + pxl;
      int yy = px >> 6, xx = px & 63;
      #pragma unroll
      for (int cc2 = 0; cc2 < 4; ++cc2) {
        unsigned off = (unsigned)(pxl * 256 + cc2 * 64 + icq * 16) ^ ((pxl & 7) << 4);
        U4 q = *(const U4*)((char*)eb + off);
        *(U4*)&Out4[(((size_t)(b * 4 + cc2)) * PLANE + (size_t)(y0 + yy + 1) * PW + xx + 2) * 32 + icq * 8] = q;
      }
    }
    __syncthreads();
  }
}

// ---- 1x1 conv via MFMA (used once for S0 precompute) ----
__global__ __launch_bounds__(256, 2) void conv1_v2(const unsigned short* __restrict__ srcA, int ncA,
                                                   const unsigned short* __restrict__ srcB, int nc,
                                                   const unsigned short* __restrict__ Wb,
                                                   const float* __restrict__ Bias, int perB,
                                                   unsigned short* __restrict__ Out4) {
  __shared__ unsigned short lds[32768];
  const int P = blockIdx.x;
  const int L = (P & 7) * 64 + (P >> 3);
  const int b = L >> 4, px0 = (L & 15) * 256;
  const int tid = threadIdx.x, l = tid & 63, w = tid >> 6;
  const int ocg = w & 1, rowg = w >> 1, l15 = l & 15, k8 = l >> 4;

  f32x4 acc[4][8];
  #pragma unroll
  for (int mf = 0; mf < 4; ++mf)
    #pragma unroll
    for (int nf = 0; nf < 8; ++nf) acc[mf][nf] = (f32x4){0.f, 0.f, 0.f, 0.f};

  for (int cc = 0; cc < nc; ++cc) {
    const unsigned short* base = (cc < ncA) ? srcA + ((size_t)(b * ncA + cc)) * PLANE * 32
                                            : srcB + ((size_t)b) * PLANE * 32;
    bf16x8 a[4];
    #pragma unroll
    for (int mf = 0; mf < 4; ++mf)
      a[mf] = *(const bf16x8*)&Wb[(((size_t)cc * 128) + ocg * 64 + mf * 16 + l15) * 32 + k8 * 8];
    #pragma unroll
    for (int nf = 0; nf < 8; ++nf) {
      int px = px0 + rowg * 128 + nf * 16 + l15;
      int y = px >> 6, x = px & 63;
      bf16x8 bv = *(const bf16x8*)&base[((size_t)(y + 1) * PW + x + 2) * 32 + k8 * 8];
      #pragma unroll
      for (int mf = 0; mf < 4; ++mf)
        acc[mf][nf] = __builtin_amdgcn_mfma_f32_16x16x32_bf16(a[mf], bv, acc[mf][nf], 0, 0, 0);
    }
  }
  const float* bp = Bias + (perB ? b * 128 : 0);
  #pragma unroll
  for (int mf = 0; mf < 4; ++mf) {
    int oc = ocg * 64 + mf * 16 + k8 * 4;
    float4 bv4 = *(const float4*)&bp[oc];
    #pragma unroll
    for (int nf = 0; nf < 8; ++nf) {
      int pxl = rowg * 128 + nf * 16 + l15;
      unsigned lo = pack2(acc[mf][nf][0] + bv4.x, acc[mf][nf][1] + bv4.y);
      unsigned hi = pack2(acc[mf][nf][2] + bv4.z, acc[mf][nf][3] + bv4.w);
      unsigned off = (unsigned)(pxl * 256 + oc * 2) ^ ((pxl & 7) << 4);
      *(uint2*)((char*)lds + off) = make_uint2(lo, hi);
    }
  }
  __syncthreads();
  #pragma unroll
  for (int cc2 = 0; cc2 < 4; ++cc2)
    #pragma unroll
    for (int it = 0; it < 4; ++it) {
      int sid = it * 256 + tid;
      int pxl = sid >> 2, icq = sid & 3;
      unsigned off = (unsigned)(pxl * 256 + cc2 * 64 + icq * 16) ^ ((pxl & 7) << 4);
      U4 q = *(const U4*)((char*)lds + off);
      int px = px0 + pxl;
      int yy = px >> 6, xx = px & 63;
      *(U4*)&Out4[(((size_t)(b * 4 + cc2)) * PLANE + (size_t)(yy + 1) * PW + xx + 2) * 32 + icq * 8] = q;
    }
}

// ---- A = silu(gn1(A)) in-place; mu/ri from raw sums ----
__global__ __launch_bounds__(256) void gn1apply_kernel(unsigned short* __restrict__ A,
                                                       const float* __restrict__ st, const float* __restrict__ gam,
                                                       const float* __restrict__ bet) {
  size_t e8 = (size_t)blockIdx.x * 256 + threadIdx.x;
  int icq = (int)(e8 & 3), x = (int)((e8 >> 2) & 63), y = (int)((e8 >> 8) & 63);
  int cc = (int)((e8 >> 14) & 3), b = (int)(e8 >> 16);
  size_t off = (((size_t)(b * 4 + cc)) * PLANE + (size_t)(y + 1) * PW + x + 2) * 32 + icq * 8;
  int ch = icq * 8;
  int g = cc * 2 + (ch >> 4);
  const float invn = 1.f / 65536.f;
  float ssum = st[(b * 8 + g) * 2], qsum = st[(b * 8 + g) * 2 + 1];
  float mu = ssum * invn;
  float ri = rsqrtf(qsum * invn - mu * mu + 1e-5f);
  int c0 = cc * 32 + ch;
  float4 g0 = *(const float4*)&gam[c0], g1 = *(const float4*)&gam[c0 + 4];
  float4 b0 = *(const float4*)&bet[c0], b1 = *(const float4*)&bet[c0 + 4];
  float gv[8] = {g0.x, g0.y, g0.z, g0.w, g1.x, g1.y, g1.z, g1.w};
  float bv[8] = {b0.x, b0.y, b0.z, b0.w, b1.x, b1.y, b1.z, b1.w};
  U4 va = *(const U4*)&A[off];
  unsigned aa[4] = {va.x, va.y, va.z, va.w};
  unsigned out[4];
  #pragma unroll
  for (int p = 0; p < 4; ++p) {
    float h0 = (bf2f((unsigned short)(aa[p] & 0xffffu)) - mu) * ri * gv[2 * p] + bv[2 * p];
    float h1 = (bf2f((unsigned short)(aa[p] >> 16)) - mu) * ri * gv[2 * p + 1] + bv[2 * p + 1];
    out[p] = pack2(silu_f(h0), silu_f(h1));
  }
  U4 q; q.x = out[0]; q.y = out[1]; q.z = out[2]; q.w = out[3];
  *(U4*)&A[off] = q;
}

// ---- S = silu(S + gn2(Bb)); mu/ri from raw sums ----
__global__ __launch_bounds__(256) void gn2add4_kernel(unsigned short* __restrict__ S, const unsigned short* __restrict__ Bb,
                                                      const float* __restrict__ st, const float* __restrict__ gam,
                                                      const float* __restrict__ bet) {
  size_t e8 = (size_t)blockIdx.x * 256 + threadIdx.x;
  int icq = (int)(e8 & 3), x = (int)((e8 >> 2) & 63), y = (int)((e8 >> 8) & 63);
  int cc = (int)((e8 >> 14) & 3), b = (int)(e8 >> 16);
  size_t off = (((size_t)(b * 4 + cc)) * PLANE + (size_t)(y + 1) * PW + x + 2) * 32 + icq * 8;
  int ch = icq * 8;
  int g = cc * 2 + (ch >> 4);
  const float invn = 1.f / 65536.f;
  float ssum = st[(b * 8 + g) * 2], qsum = st[(b * 8 + g) * 2 + 1];
  float mu = ssum * invn;
  float ri = rsqrtf(qsum * invn - mu * mu + 1e-5f);
  int c0 = cc * 32 + ch;
  float4 g0 = *(const float4*)&gam[c0], g1 = *(const float4*)&gam[c0 + 4];
  float4 b0 = *(const float4*)&bet[c0], b1 = *(const float4*)&bet[c0 + 4];
  float gv[8] = {g0.x, g0.y, g0.z, g0.w, g1.x, g1.y, g1.z, g1.w};
  float bv[8] = {b0.x, b0.y, b0.z, b0.w, b1.x, b1.y, b1.z, b1.w};
  U4 vb = *(const U4*)&Bb[off];
  U4 vs = *(const U4*)&S[off];
  unsigned ab[4] = {vb.x, vb.y, vb.z, vb.w};
  unsigned as[4] = {vs.x, vs.y, vs.z, vs.w};
  unsigned out[4];
  #pragma unroll
  for (int p = 0; p < 4; ++p) {
    float h0 = (bf2f((unsigned short)(ab[p] & 0xffffu)) - mu) * ri * gv[2 * p] + bv[2 * p];
    float h1 = (bf2f((unsigned short)(ab[p] >> 16)) - mu) * ri * gv[2 * p + 1] + bv[2 * p + 1];
    float r0 = silu_f(bf2f((unsigned short)(as[p] & 0xffffu)) + h0);
    float r1 = silu_f(bf2f((unsigned short)(as[p] >> 16)) + h1);
    out[p] = pack2(r0, r1);
  }
  U4 q; q.x = out[0]; q.y = out[1]; q.z = out[2]; q.w = out[3];
  *(U4*)&S[off] = q;
}

// ---- fused grid_sample + out_proj: rd[t][oc] = ob[oc] + sum_ic wo[oc][ic] * bilerp(S)[t][ic] ----
__global__ __launch_bounds__(256) void gsample_op_kernel(const unsigned short* __restrict__ S4,
                                                         const float* __restrict__ x,
                                                         const unsigned short* __restrict__ wo,
                                                         const float* __restrict__ ob,
                                                         float* __restrict__ rd) {
  __shared__ float sv[2][128];
  int tid = threadIdx.x;
  int tt = tid >> 7, c = tid & 127;
  int token = blockIdx.x * 2 + tt;
  int b = token >> 8;
  {
    float cx = x[token * 2], cy = x[token * 2 + 1];
    float fx = (cx + 1.f) * 32.f - 0.5f;
    float fy = (cy + 1.f) * 32.f - 0.5f;
    float x0f = floorf(fx), y0f = floorf(fy);
    float wx = fx - x0f, wy = fy - y0f;
    const unsigned short* Sb = S4 + ((size_t)(b * 4 + (c >> 5)) * PLANE) * 32 + (c & 31);
    float acc = 0.f;
    #pragma unroll
    for (int cor = 0; cor < 4; ++cor) {
      float xi = x0f + (float)(cor & 1), yi = y0f + (float)(cor >> 1);
      float wgt = ((cor & 1) ? wx : 1.f - wx) * ((cor >> 1) ? wy : 1.f - wy);
      if (xi >= 0.f && xi <= 63.f && yi >= 0.f && yi <= 63.f)
        acc += bf2f(Sb[(size_t)(((int)yi + 1) * PW + (int)xi + 2) * 32]) * wgt;
    }
    sv[tt][c] = acc;
  }
  __syncthreads();
  {
    int oc = c;
    float acc = ob[oc];
    #pragma unroll
    for (int cc = 0; cc < 4; ++cc) {
      #pragma unroll
      for (int q8 = 0; q8 < 4; ++q8) {
        U4 wq = *(const U4*)&wo[(size_t)cc * 4096 + oc * 32 + q8 * 8];
        unsigned a[4] = {wq.x, wq.y, wq.z, wq.w};
        const float* sp = &sv[tt][cc * 32 + q8 * 8];
        #pragma unroll
        for (int p = 0; p < 4; ++p) {
          acc += bf2f((unsigned short)(a[p] & 0xffffu)) * sp[2 * p];
          acc += bf2f((unsigned short)(a[p] >> 16)) * sp[2 * p + 1];
        }
      }
    }
    rd[(size_t)token * 128 + oc] = acc;
  }
}

__global__ __launch_bounds__(256) void mlp_fc_kernel(const float* __restrict__ in, const float* __restrict__ w,
                                                     const float* __restrict__ init, int initPerB,
                                                     float* __restrict__ out) {
  int tok0 = blockIdx.x * 2;
  int tid = threadIdx.x;
  __shared__ float sr[2][128];
  sr[tid >> 7][tid & 127] = in[(size_t)tok0 * 128 + tid];
  __syncthreads();
  int t = tid >> 7, j = tid & 127;
  int token = tok0 + t;
  int b = token >> 8;
  float acc = initPerB ? init[b * 128 + j] : init[j];
  #pragma unroll 8
  for (int k = 0; k < 128; ++k) acc += sr[t][k] * w[(size_t)k * 128 + j];
  out[(size_t)token * 128 + j] = silu_f(acc);
}

__global__ __launch_bounds__(256) void mlp3_update_kernel(const float* __restrict__ h2, const float* __restrict__ w3,
                                                          const float* __restrict__ b3, float* __restrict__ x) {
  int token = blockIdx.x * 256 + threadIdx.x;
  if (token >= BN * TN) return;
  float d0 = b3[0], d1 = b3[1];
  const float* h = h2 + (size_t)token * 128;
  #pragma unroll 8
  for (int k = 0; k < 128; ++k) { float hv = h[k]; d0 += hv * w3[k * 2]; d1 += hv * w3[k * 2 + 1]; }
  float nx = x[token * 2] + 0.2f * d0;
  float ny = x[token * 2 + 1] + 0.2f * d1;
  x[token * 2] = fminf(fmaxf(nx, -1.f), 1.f);
  x[token * 2 + 1] = fminf(fmaxf(ny, -1.f), 1.f);
}

extern "C" void kernel_launch(void* const* d_in, const int* in_sizes, int n_in,
                              void* d_out, int out_size, void* d_ws, size_t ws_size,
                              hipStream_t stream) {
  const float* M   = (const float*)d_in[0];
  const float* x0  = (const float*)d_in[1];
  const float* te  = (const float*)d_in[2];
  const float* ipw = (const float*)d_in[3];
  const float* ipb = (const float*)d_in[4];
  const float* c1w = (const float*)d_in[5];
  const float* c1b = (const float*)d_in[6];
  const float* g1w = (const float*)d_in[7];
  const float* g1b = (const float*)d_in[8];
  const float* c2w = (const float*)d_in[9];
  const float* c2b = (const float*)d_in[10];
  const float* g2w = (const float*)d_in[11];
  const float* g2b = (const float*)d_in[12];
  const float* ow  = (const float*)d_in[13];
  const float* ob  = (const float*)d_in[14];
  const float* w1  = (const float*)d_in[15];
  const float* b1  = (const float*)d_in[16];
  const float* w2  = (const float*)d_in[17];
  const float* b2  = (const float*)d_in[18];
  const float* w3  = (const float*)d_in[19];
  const float* b3  = (const float*)d_in[20];

  const size_t PSH = (size_t)PLANE * 32;
  float* f     = (float*)d_ws;
  float* wx    = f;
  float* tctr  = wx + 16384;
  float* tpart = tctr + 4096;
  float* stats = tpart + 4096;     // 18 slices x 512 raw sums
  float* rd    = stats + 9216;
  float* h1    = rd + 1048576;
  float* h2    = h1 + 1048576;
  unsigned short* S4  = (unsigned short*)(h2 + 1048576);
  unsigned short* A4  = S4 + 128 * PSH;
  unsigned short* B4  = A4 + 128 * PSH;
  unsigned short* S0  = B4 + 128 * PSH;
  unsigned short* Ms4 = S0 + 128 * PSH;
  unsigned short* Pp  = Ms4 + 64 * PSH;
  unsigned short* wc  = Pp + 32 * PSH;
  unsigned short* wi  = wc + 884736;
  unsigned short* wo  = wi + 12288;

  copy_kernel<<<64, 256, 0, stream>>>(x0, wx, 16384);
  zstats_kernel<<<36, 256, 0, stream>>>(stats);
  zerohalo_kernel<<<2352, 256, 0, stream>>>(S4);   // S4,A4,B4 halos
  resize_t_kernel<<<dim3(16, 32), 256, 0, stream>>>(M, Ms4);
  tctr_kernel<<<16, 256, 0, stream>>>(ipw, ipb, te, tctr);
  tpart_kernel<<<16, 256, 0, stream>>>(w1, b1, te, tpart);
  for (int i = 0; i < 3; ++i) {
    wprep_kernel<<<576, 256, 0, stream>>>(c1w + (size_t)i * 147456, wc + (size_t)(2 * i) * 147456);
    wprep_kernel<<<576, 256, 0, stream>>>(c2w + (size_t)i * 147456, wc + (size_t)(2 * i + 1) * 147456);
  }
  wprep_in_kernel<<<48, 256, 0, stream>>>(ipw, wi);
  wprep_out_kernel<<<64, 256, 0, stream>>>(ow, wo);
  // S0 = W_Ms * Ms + tctr  (loop-invariant part of in_proj, computed once)
  conv1_v2<<<512, 256, 0, stream>>>(Ms4, 2, nullptr, 2, wi, tctr, 1, S0);

  for (int r = 0; r < 3; ++r) {
    raster4_kernel<<<dim3(16, 32), 256, 0, stream>>>(wx, Pp);
    inproj_fast_kernel<<<8192, 256, 0, stream>>>(S0, Pp, ipw, S4);
    for (int i = 0; i < 3; ++i) {
      float* stA = stats + (size_t)(r * 3 + i) * 512;
      float* stB = stats + (size_t)(9 + r * 3 + i) * 512;
      conv3_v8<<<512, 512, 0, stream>>>(S4, wc + (size_t)(2 * i) * 147456, c1b + i * 128, stA, A4);
      gn1apply_kernel<<<8192, 256, 0, stream>>>(A4, stA, g1w + i * 128, g1b + i * 128);
      conv3_v8<<<512, 512, 0, stream>>>(A4, wc + (size_t)(2 * i + 1) * 147456, c2b + i * 128, stB, B4);
      gn2add4_kernel<<<8192, 256, 0, stream>>>(S4, B4, stB, g2w + i * 128, g2b + i * 128);
    }
    gsample_op_kernel<<<4096, 256, 0, stream>>>(S4, wx, wo, ob, rd);
    mlp_fc_kernel<<<4096, 256, 0, stream>>>(rd, w1, tpart, 1, h1);
    mlp_fc_kernel<<<4096, 256, 0, stream>>>(h1, w2, b2, 0, h2);
    mlp3_update_kernel<<<32, 256, 0, stream>>>(h2, w3, b3, wx);
  }
  copy_kernel<<<64, 256, 0, stream>>>(wx, (float*)d_out, 16384);
}